// Round 16
// baseline (108.385 us; speedup 1.0000x reference)
//
#include <hip/hip_runtime.h>
#include <hip/hip_bf16.h>

// Problem constants: B=4, S=4096, D=1024, T=16, TD=64, K=4
typedef float floatx4 __attribute__((ext_vector_type(4)));
typedef __bf16 bf16x8 __attribute__((ext_vector_type(8)));

__device__ __forceinline__ unsigned short f2bf(float f){
  unsigned u = __builtin_bit_cast(unsigned, f);
  u += 0x7fffu + ((u >> 16) & 1u);
  return (unsigned short)(u >> 16);
}
__device__ __forceinline__ unsigned pk2(float a, float b){
  return (unsigned)f2bf(a) | ((unsigned)f2bf(b) << 16);
}
__device__ __forceinline__ float wred64(float v){
  v += __shfl_xor(v, 32); v += __shfl_xor(v, 16); v += __shfl_xor(v, 8);
  v += __shfl_xor(v, 4);  v += __shfl_xor(v, 2);  v += __shfl_xor(v, 1);
  return v;
}
// tanh-form GELU via hardware exp2/rcp (|err| vs exact-erf < 1e-3, threshold 0.142)
__device__ __forceinline__ float gelu_f(float v){
  float u = v * v;
  float y = v * __builtin_fmaf(u, 0.0356774081f, 0.7978845608f);
  float a = __builtin_fabsf(y);
  float t = __builtin_amdgcn_exp2f(-2.8853900818f * a);   // e^{-2|y|}
  float th = (1.0f - t) * __builtin_amdgcn_rcpf(1.0f + t);
  return 0.5f * (v + __builtin_fabsf(v) * th);
}

// ---------------- K1: LN partials + W1/W2 convert (r13-EXACT, proven best) ----------------
__global__ __launch_bounds__(256) void wk_ln_part(const float* __restrict__ x,
    const float* __restrict__ gm, const float* __restrict__ bt, float* __restrict__ part,
    const float* __restrict__ W1, const float* __restrict__ W2,
    unsigned short* __restrict__ W1bf, unsigned short* __restrict__ W2bf){
  __shared__ float red[4][1024];
  const int tid = threadIdx.x, w = tid >> 6, lane = tid & 63;
  const int blk = blockIdx.x;
  if (blk < 64){
    for (int i = blk*256 + tid; i < 128*320; i += 64*256) W1bf[i] = f2bf(W1[i]);
    for (int i = blk*256 + tid; i < 64*128;  i += 64*256) W2bf[i] = f2bf(W2[i]);
  }
  floatx4 gv[4], bv[4];
#pragma unroll
  for (int j = 0; j < 4; ++j){
    gv[j] = *(const floatx4*)(gm + j*256 + lane*4);
    bv[j] = *(const floatx4*)(bt + j*256 + lane*4);
  }
  floatx4 acc[4];
#pragma unroll
  for (int j = 0; j < 4; ++j){ acc[j][0]=0.f; acc[j][1]=0.f; acc[j][2]=0.f; acc[j][3]=0.f; }
  const int row0 = blk*32 + w*8;
#pragma unroll 2
  for (int r = 0; r < 8; ++r){
    const float* xr = x + (size_t)(row0 + r) * 1024;
    floatx4 xv[4];
#pragma unroll
    for (int j = 0; j < 4; ++j) xv[j] = *(const floatx4*)(xr + j*256 + lane*4);
    float s = 0.f, s2 = 0.f;
#pragma unroll
    for (int j = 0; j < 4; ++j)
#pragma unroll
      for (int e = 0; e < 4; ++e){ float v = xv[j][e]; s += v; s2 += v*v; }
    s = wred64(s); s2 = wred64(s2);
    const float mu = s * (1.0f/1024.0f);
    const float rs = rsqrtf(s2 * (1.0f/1024.0f) - mu*mu + 1e-5f);
#pragma unroll
    for (int j = 0; j < 4; ++j)
#pragma unroll
      for (int e = 0; e < 4; ++e)
        acc[j][e] += (xv[j][e] - mu) * rs * gv[j][e] + bv[j][e];
  }
#pragma unroll
  for (int j = 0; j < 4; ++j) *(floatx4*)(&red[w][j*256 + lane*4]) = acc[j];
  __syncthreads();
  const int p = tid * 4;
  floatx4 s0 = *(const floatx4*)(&red[0][p]);
  floatx4 s1 = *(const floatx4*)(&red[1][p]);
  floatx4 s2v = *(const floatx4*)(&red[2][p]);
  floatx4 s3 = *(const floatx4*)(&red[3][p]);
  *(floatx4*)(part + (size_t)blk*1024 + p) = s0 + s1 + s2v + s3;
}

// ---------------- K2 v3: per-batch reduce + routing, full-lane parallel ----------------
// Reduce + top-4 phases byte-identical to r14. q/k: thread (w,sg,pair) computes 4 dims
// (per-dot inner loop bit-exact: serial j=0..63 from bq[d]); Wq/Wk staged in LDS.
// Scores: 256 threads, 1 dot each, same serial dd order. Only the sq/sk association
// changes (1e-7 on iq) — canary: absmax must stay exactly 0.03125.
__global__ __launch_bounds__(256) void wk_redroute(const float* __restrict__ part,
    const float* __restrict__ Wq, const float* __restrict__ bq,
    const float* __restrict__ Wk, const float* __restrict__ bk, int* __restrict__ routes){
  __shared__ float tr[1024];            // swizzled: word = tile*64 + (jw ^ ((tile&7)<<2))
  __shared__ float wqs[4096], wks[4096];// 64x64 f32 staged weights
  __shared__ float qnt[1024], knt[1024];// [d][tile] 64x16
  __shared__ float redq[16][16], redk[16][16];  // [w*4+sg][tile]
  __shared__ float iqa[16], ika[16];
  __shared__ float scs[256];            // [tile][u]
  const int t = threadIdx.x, w = t >> 6, lane = t & 63, b = blockIdx.x;
  // stage Wq/Wk -> LDS (coalesced)
#pragma unroll
  for (int i = 0; i < 16; ++i){
    wqs[t + i*256] = Wq[t + i*256];
    wks[t + i*256] = Wk[t + i*256];
  }
  // ---- reduce (EXACT r14 order)
  {
    floatx4 sg4[4];
#pragma unroll
    for (int g = 0; g < 4; ++g){
      sg4[g][0]=0.f; sg4[g][1]=0.f; sg4[g][2]=0.f; sg4[g][3]=0.f;
      for (int i = 0; i < 32; ++i)
        sg4[g] += *(const floatx4*)(part + (size_t)(b*128 + g*32 + i)*1024 + t*4);
    }
    const floatx4 tot = ((sg4[0] + sg4[1]) + sg4[2]) + sg4[3];
    const floatx4 tv = tot * (1.0f/4096.0f);
    const int row = t >> 4, jw0 = (t & 15)*4;
    *(floatx4*)(&tr[row*64 + (jw0 ^ ((row & 7) << 2))]) = tv;
  }
  __syncthreads();
  // ---- q/k linears: thread (w, sg=lane>>4, pair=lane&15) -> dims w*16+sg*4..+3 of tile 'pair'
  const int pair = lane & 15, sgi = lane >> 4;
  float trv[64];
  {
    const int sw = (pair & 7) << 2;
#pragma unroll
    for (int j = 0; j < 16; ++j){
      const floatx4 v = *(const floatx4*)(&tr[pair*64 + ((j*4) ^ sw)]);
      trv[j*4+0]=v[0]; trv[j*4+1]=v[1]; trv[j*4+2]=v[2]; trv[j*4+3]=v[3];
    }
  }
  float qv[4], kv[4], sq = 0.f, sk = 0.f;
#pragma unroll
  for (int di = 0; di < 4; ++di){
    const int d = w*16 + sgi*4 + di;
    const float* wqr = wqs + d*64;
    const float* wkr = wks + d*64;
    float aq = bq[d], ak = bk[d];
#pragma unroll
    for (int j = 0; j < 64; ++j){
      aq = __builtin_fmaf(wqr[j], trv[j], aq);
      ak = __builtin_fmaf(wkr[j], trv[j], ak);
    }
    qv[di] = aq; kv[di] = ak; sq += aq*aq; sk += ak*ak;
  }
  redq[w*4 + sgi][pair] = sq; redk[w*4 + sgi][pair] = sk;
  __syncthreads();
  if (t < 16){
    float s0 = redq[0][t], s1 = redk[0][t];
#pragma unroll
    for (int u = 1; u < 16; ++u){ s0 += redq[u][t]; s1 += redk[u][t]; }
    iqa[t] = 1.0f / fmaxf(sqrtf(s0), 1e-12f);
    ika[t] = 1.0f / fmaxf(sqrtf(s1), 1e-12f);
  }
  __syncthreads();
  {
    const float iq = iqa[pair], ik = ika[pair];
#pragma unroll
    for (int di = 0; di < 4; ++di){
      const int d = w*16 + sgi*4 + di;
      qnt[d*16 + pair] = qv[di]*iq;
      knt[d*16 + pair] = kv[di]*ik;
    }
  }
  __syncthreads();
  // ---- scores: thread t -> (tile tt = t>>4, u = t&15), serial dd order (v2-exact)
  {
    const int tt = t >> 4, u = t & 15;
    float s = 0.f;
#pragma unroll
    for (int dd = 0; dd < 64; ++dd)
      s = __builtin_fmaf(qnt[dd*16 + tt], knt[dd*16 + u], s);
    scs[tt*16 + u] = s;
  }
  __syncthreads();
  // ---- stable top-4 (EXACT r14)
  if (t < 16){
    float sc[16];
#pragma unroll
    for (int u = 0; u < 16; ++u) sc[u] = scs[t*16 + u];
    sc[t] = -3.0e38f;
    for (int kk = 0; kk < 4; ++kk){
      float best = -3.4e38f; int bi = 0;
#pragma unroll
      for (int u = 0; u < 16; ++u) if (sc[u] > best){ best = sc[u]; bi = u; }
      routes[(b*16 + t)*4 + kk] = bi;
      sc[bi] = -3.4e38f;
    }
  }
}

// ---------------- K3: fused LN + wormhole-MLP + residual (r13-EXACT, proven) ------------
// 512 blocks x 8 quads, LDS 40960, bounds (256,2). Envelope locked (r4-r12 ledger).
#define MFMA16(accv, av, bbv) accv = __builtin_amdgcn_mfma_f32_16x16x32_bf16(av, bbv, accv, 0, 0, 0)

__global__ __launch_bounds__(256, 2) void wk_main(const float* __restrict__ x,
    const float* __restrict__ gm, const float* __restrict__ bt,
    const float* __restrict__ b1, const float* __restrict__ b2p,
    const unsigned short* __restrict__ W1bf, const unsigned short* __restrict__ W2bf,
    const int* __restrict__ routes, float* __restrict__ out){
  __shared__ char sm[40960];
  const int tid = threadIdx.x, w = tid >> 6, lane = tid & 63;
  const int c = lane & 15, g = lane >> 4;
  char* xnb = sm;            // [row r][2048B], XOR-swizzled by tile
  char* Hb  = sm + 8192;     // [row r][4096B]: [tile c][dim*2], XOR (c&7)<<4
  char* W2s = sm + 24576;    // [64 rows][256B], XOR (row&7)<<4
#pragma unroll
  for (int q = 0; q < 4; ++q){
    const int cid = tid*4 + q, row = cid >> 4, k16 = cid & 15;
    *(int4*)(W2s + row*256 + ((k16*16) ^ ((row & 7) << 4))) = *(const int4*)(W2bf + row*128 + k16*8);
  }
  // W1 m-slice -> registers: lane (c,g) holds W1[(2w+mi)*16+c][kk*32+g*8+e]
  bf16x8 w1f[2][10];
#pragma unroll
  for (int mi = 0; mi < 2; ++mi)
#pragma unroll
    for (int kk = 0; kk < 10; ++kk)
      w1f[mi][kk] = *(const bf16x8*)(W1bf + ((2*w + mi)*16 + c)*320 + kk*32 + g*8);
  floatx4 gvv[4], bvv[4];
#pragma unroll
  for (int j = 0; j < 4; ++j){
    gvv[j] = *(const floatx4*)(gm + j*256 + lane*4);
    bvv[j] = *(const floatx4*)(bt + j*256 + lane*4);
  }
  floatx4 b1v[2];
#pragma unroll
  for (int mi = 0; mi < 2; ++mi) b1v[mi] = *(const floatx4*)(b1 + (2*w + mi)*16 + g*4);
  float b2v[4];
#pragma unroll
  for (int nn = 0; nn < 4; ++nn) b2v[nn] = b2p[nn*16 + c];
  const int bbat = blockIdx.x >> 7;    // 128 blocks per batch
  const int4 rt4 = *(const int4*)(routes + (bbat*16 + c)*4);
  const int rts[5] = {c, rt4.x, rt4.y, rt4.z, rt4.w};
  const int swc = (c & 7) << 4;
  const int g16 = g * 16;

#pragma unroll 1
  for (int q = 0; q < 8; ++q){
    const int row = blockIdx.x*32 + q*4 + w;
    // ---- LN for this wave's row (coalesced float4), keep x in regs for residual
    const float* xr = x + (size_t)row * 1024;
    floatx4 xv[4];
#pragma unroll
    for (int j = 0; j < 4; ++j) xv[j] = *(const floatx4*)(xr + j*256 + lane*4);
    float s = 0.f, s2 = 0.f;
#pragma unroll
    for (int j = 0; j < 4; ++j)
#pragma unroll
      for (int e = 0; e < 4; ++e){ float v = xv[j][e]; s += v; s2 += v*v; }
    s = wred64(s); s2 = wred64(s2);
    const float mu = s * (1.0f/1024.0f);
    const float rs = rsqrtf(s2 * (1.0f/1024.0f) - mu*mu + 1e-5f);
#pragma unroll
    for (int j = 0; j < 4; ++j){
      floatx4 xn = (xv[j] - mu) * rs * gvv[j] + bvv[j];
      uint2 pv; pv.x = pk2(xn[0], xn[1]); pv.y = pk2(xn[2], xn[3]);
      const int o = j*512 + lane*8;
      *(uint2*)(xnb + w*2048 + (o ^ (((o >> 7) & 7) << 4))) = pv;
    }
    __syncthreads();   // bar A: xn visible
    // ---- GEMM1: H[m-slice][tile c] for 4 quad-rows, W1 from regs, xn from LDS
    floatx4 acc[4][2];
#pragma unroll
    for (int r = 0; r < 4; ++r)
#pragma unroll
      for (int mi = 0; mi < 2; ++mi){ acc[r][mi][0]=0.f; acc[r][mi][1]=0.f; acc[r][mi][2]=0.f; acc[r][mi][3]=0.f; }
#pragma unroll
    for (int kk = 0; kk < 10; ++kk){
      const int s_ = rts[kk >> 1];
      const int baddr = (s_*128 + (kk & 1)*64 + g16) ^ ((s_ & 7) << 4);
      bf16x8 bfr[4];
#pragma unroll
      for (int r = 0; r < 4; ++r) bfr[r] = *(const bf16x8*)(xnb + r*2048 + baddr);
#pragma unroll
      for (int r = 0; r < 4; ++r)
#pragma unroll
        for (int mi = 0; mi < 2; ++mi)
          MFMA16(acc[r][mi], w1f[mi][kk], bfr[r]);
    }
    // ---- bias + GELU -> Hb (bf16)
#pragma unroll
    for (int r = 0; r < 4; ++r)
#pragma unroll
      for (int mi = 0; mi < 2; ++mi){
        floatx4 z = acc[r][mi] + b1v[mi];
        uint2 pv; pv.x = pk2(gelu_f(z[0]), gelu_f(z[1])); pv.y = pk2(gelu_f(z[2]), gelu_f(z[3]));
        *(uint2*)(Hb + r*4096 + c*256 + ((((2*w + mi)*32) + g*8) ^ swc)) = pv;
      }
    __syncthreads();   // bar B: H visible
    // ---- GEMM2 for this wave's row (Hb[w] + W2s)
    floatx4 a2c[4];
#pragma unroll
    for (int n = 0; n < 4; ++n){ a2c[n][0]=0.f; a2c[n][1]=0.f; a2c[n][2]=0.f; a2c[n][3]=0.f; }
#pragma unroll
    for (int k2 = 0; k2 < 4; ++k2){
      const bf16x8 a2 = *(const bf16x8*)(Hb + w*4096 + c*256 + (((k2*64) + g16) ^ swc));
#pragma unroll
      for (int n = 0; n < 4; ++n){
        const bf16x8 b2f = *(const bf16x8*)(W2s + (n*16 + c)*256 + (((k2*64) + g16) ^ swc));
        MFMA16(a2c[n], a2, b2f);
      }
    }
    // ---- O -> LDS (overlay Hb[w], wave-private, XOR word idx by (orow&7)<<2) -> float4 store
    float* Ob = (float*)(Hb + w*4096);
#pragma unroll
    for (int n = 0; n < 4; ++n)
#pragma unroll
      for (int reg = 0; reg < 4; ++reg){
        const int orow = g*4 + reg;
        Ob[orow*64 + ((n*16 + c) ^ ((orow & 7) << 2))] = a2c[n][reg] + b2v[n];
      }
    float* op = out + (size_t)row * 1024;
#pragma unroll
    for (int j = 0; j < 4; ++j){
      const int orow = j*4 + g;
      const floatx4 ov = *(const floatx4*)(Ob + orow*64 + ((c*4) ^ ((orow & 7) << 2)));
      *(floatx4*)(op + j*256 + lane*4) = ov + xv[j];
    }
    __syncthreads();   // bar C
  }
}

extern "C" void kernel_launch(void* const* d_in, const int* in_sizes, int n_in,
                              void* d_out, int out_size, void* d_ws, size_t ws_size,
                              hipStream_t stream){
  const float* x  = (const float*)d_in[0];
  const float* gm = (const float*)d_in[1];
  const float* bt = (const float*)d_in[2];
  const float* Wq = (const float*)d_in[3];
  const float* bq = (const float*)d_in[4];
  const float* Wk = (const float*)d_in[5];
  const float* bk = (const float*)d_in[6];
  const float* W1 = (const float*)d_in[7];
  const float* b1 = (const float*)d_in[8];
  const float* W2 = (const float*)d_in[9];
  const float* b2 = (const float*)d_in[10];
  float* out = (float*)d_out;
  char* ws = (char*)d_ws;
  float* part = (float*)ws;                         // 512*1024 f32 = 2MB
  int*   routes = (int*)(ws + 2097152);             // 256 i32
  unsigned short* W1bf = (unsigned short*)(ws + 2114560);  // 40960 bf16 (linear)
  unsigned short* W2bf = (unsigned short*)(ws + 2196480);  // 8192 bf16 (linear)

  wk_ln_part<<<512, 256, 0, stream>>>(x, gm, bt, part, W1, W2, W1bf, W2bf);
  wk_redroute<<<4, 256, 0, stream>>>(part, Wq, bq, Wk, bk, routes);
  wk_main<<<512, 256, 0, stream>>>(x, gm, bt, b1, b2, W1bf, W2bf, routes, out);
}

// Round 17
// 94.184 us; speedup vs baseline: 1.1508x; 1.1508x over previous
//
#include <hip/hip_runtime.h>
#include <hip/hip_bf16.h>

// Problem constants: B=4, S=4096, D=1024, T=16, TD=64, K=4
typedef float floatx4 __attribute__((ext_vector_type(4)));
typedef __bf16 bf16x8 __attribute__((ext_vector_type(8)));

__device__ __forceinline__ unsigned short f2bf(float f){
  unsigned u = __builtin_bit_cast(unsigned, f);
  u += 0x7fffu + ((u >> 16) & 1u);
  return (unsigned short)(u >> 16);
}
__device__ __forceinline__ unsigned pk2(float a, float b){
  return (unsigned)f2bf(a) | ((unsigned)f2bf(b) << 16);
}
__device__ __forceinline__ float wred64(float v){
  v += __shfl_xor(v, 32); v += __shfl_xor(v, 16); v += __shfl_xor(v, 8);
  v += __shfl_xor(v, 4);  v += __shfl_xor(v, 2);  v += __shfl_xor(v, 1);
  return v;
}
// tanh-form GELU via hardware exp2/rcp (|err| vs exact-erf < 1e-3, threshold 0.142)
__device__ __forceinline__ float gelu_f(float v){
  float u = v * v;
  float y = v * __builtin_fmaf(u, 0.0356774081f, 0.7978845608f);
  float a = __builtin_fabsf(y);
  float t = __builtin_amdgcn_exp2f(-2.8853900818f * a);   // e^{-2|y|}
  float th = (1.0f - t) * __builtin_amdgcn_rcpf(1.0f + t);
  return 0.5f * (v + __builtin_fabsf(v) * th);
}

// ---------------- K1: LN + per-block tile-sum partials (deterministic) ----------------
__global__ __launch_bounds__(256) void wk_ln_part(const float* __restrict__ x,
    const float* __restrict__ gm, const float* __restrict__ bt, float* __restrict__ part){
  __shared__ float red[4][1024];
  const int tid = threadIdx.x, w = tid >> 6, lane = tid & 63;
  const int blk = blockIdx.x;
  floatx4 gv[4], bv[4];
#pragma unroll
  for (int j = 0; j < 4; ++j){
    gv[j] = *(const floatx4*)(gm + j*256 + lane*4);
    bv[j] = *(const floatx4*)(bt + j*256 + lane*4);
  }
  floatx4 acc[4];
#pragma unroll
  for (int j = 0; j < 4; ++j){ acc[j][0]=0.f; acc[j][1]=0.f; acc[j][2]=0.f; acc[j][3]=0.f; }
  const int row0 = blk*32 + w*8;
#pragma unroll 2
  for (int r = 0; r < 8; ++r){
    const float* xr = x + (size_t)(row0 + r) * 1024;
    floatx4 xv[4];
#pragma unroll
    for (int j = 0; j < 4; ++j) xv[j] = *(const floatx4*)(xr + j*256 + lane*4);
    float s = 0.f, s2 = 0.f;
#pragma unroll
    for (int j = 0; j < 4; ++j)
#pragma unroll
      for (int e = 0; e < 4; ++e){ float v = xv[j][e]; s += v; s2 += v*v; }
    s = wred64(s); s2 = wred64(s2);
    const float mu = s * (1.0f/1024.0f);
    const float rs = rsqrtf(s2 * (1.0f/1024.0f) - mu*mu + 1e-5f);
#pragma unroll
    for (int j = 0; j < 4; ++j)
#pragma unroll
      for (int e = 0; e < 4; ++e)
        acc[j][e] += (xv[j][e] - mu) * rs * gv[j][e] + bv[j][e];
  }
#pragma unroll
  for (int j = 0; j < 4; ++j) *(floatx4*)(&red[w][j*256 + lane*4]) = acc[j];
  __syncthreads();
  const int p = tid * 4;
  floatx4 s0 = *(const floatx4*)(&red[0][p]);
  floatx4 s1 = *(const floatx4*)(&red[1][p]);
  floatx4 s2v = *(const floatx4*)(&red[2][p]);
  floatx4 s3 = *(const floatx4*)(&red[3][p]);
  *(floatx4*)(part + (size_t)blk*1024 + p) = s0 + s1 + s2v + s3;
}

// ---------------- K2a: reduce partials -> tile_repr; convert W1/W2 to bf16 ----------------
__global__ __launch_bounds__(256) void wk_reduce(const float* __restrict__ part, float* __restrict__ trep,
    const float* __restrict__ W1, const float* __restrict__ W2,
    unsigned short* __restrict__ W1bf, unsigned short* __restrict__ W2bf){
  __shared__ float red[4][64];
  const int j = blockIdx.x, b = j >> 4, chunk = j & 15;
  const int t = threadIdx.x, po = t & 63, part4 = t >> 6;
  const int p = chunk*64 + po;
  float s = 0.f;
  for (int i = 0; i < 32; ++i) s += part[(size_t)(b*128 + part4*32 + i)*1024 + p];
  red[part4][po] = s;
  __syncthreads();
  if (t < 64) trep[b*1024 + chunk*64 + t] = red[0][t] + red[1][t] + red[2][t] + red[3][t];
  for (int i = j*256 + t; i < 128*320; i += 64*256) W1bf[i] = f2bf(W1[i]);
  for (int i = j*256 + t; i < 64*128;  i += 64*256) W2bf[i] = f2bf(W2[i]);
}

// ---------------- K2b: routing v2 (scalar-path weights, wave=dim-slice, lane=pair) ------
__global__ __launch_bounds__(256) void wk_route(const float* __restrict__ trep,
    const float* __restrict__ Wq, const float* __restrict__ bq,
    const float* __restrict__ Wk, const float* __restrict__ bk, int* __restrict__ routes){
  __shared__ float tr[4096];          // swizzled: word = pair*64 + (jw ^ ((pair&7)<<2))
  __shared__ float qnt[4096], knt[4096];  // transposed: [d][pair]
  __shared__ float redq[4][64], redk[4][64];
  __shared__ float scs[1024];         // [pair][u]
  const int t = threadIdx.x, w = t >> 6, lane = t & 63;
  for (int i = t; i < 4096; i += 256){
    const int row = i >> 6, jw = i & 63;
    tr[row*64 + (jw ^ ((row & 7) << 2))] = trep[i] * (1.0f/4096.0f);
  }
  __syncthreads();
  float trv[64];
  {
    const int sw = (lane & 7) << 2;
#pragma unroll
    for (int j = 0; j < 16; ++j){
      const floatx4 v = *(const floatx4*)(&tr[lane*64 + ((j*4) ^ sw)]);
      trv[j*4+0]=v[0]; trv[j*4+1]=v[1]; trv[j*4+2]=v[2]; trv[j*4+3]=v[3];
    }
  }
  float qv[16], kv[16], sq = 0.f, sk = 0.f;
#pragma unroll 4
  for (int dd = 0; dd < 16; ++dd){
    const int d = __builtin_amdgcn_readfirstlane(w*16 + dd);
    const float* wqr = Wq + d*64;
    const float* wkr = Wk + d*64;
    float aq = bq[d], ak = bk[d];
#pragma unroll
    for (int j = 0; j < 64; ++j){
      aq = __builtin_fmaf(wqr[j], trv[j], aq);
      ak = __builtin_fmaf(wkr[j], trv[j], ak);
    }
    qv[dd] = aq; kv[dd] = ak; sq += aq*aq; sk += ak*ak;
  }
  redq[w][lane] = sq; redk[w][lane] = sk;
  __syncthreads();
  const float nq = sqrtf(redq[0][lane]+redq[1][lane]+redq[2][lane]+redq[3][lane]);
  const float nk = sqrtf(redk[0][lane]+redk[1][lane]+redk[2][lane]+redk[3][lane]);
  const float iq = 1.0f / fmaxf(nq, 1e-12f), ik = 1.0f / fmaxf(nk, 1e-12f);
#pragma unroll
  for (int dd = 0; dd < 16; ++dd){
    qnt[(w*16 + dd)*64 + lane] = qv[dd]*iq;
    knt[(w*16 + dd)*64 + lane] = kv[dd]*ik;
  }
  __syncthreads();
  {
    const int sidx = t*4, b = sidx >> 8, tt = (sidx >> 4) & 15, uu0 = sidx & 15;
    const int qp = b*16 + tt;
    float qrow[64];
#pragma unroll
    for (int dd = 0; dd < 64; ++dd) qrow[dd] = qnt[dd*64 + qp];
#pragma unroll
    for (int e = 0; e < 4; ++e){
      const int kp = b*16 + uu0 + e;
      float s = 0.f;
#pragma unroll
      for (int dd = 0; dd < 64; ++dd) s = __builtin_fmaf(qrow[dd], knt[dd*64 + kp], s);
      scs[qp*16 + uu0 + e] = s;
    }
  }
  __syncthreads();
  if (t < 64){
    const int tt = t & 15;
    float sc[16];
#pragma unroll
    for (int u = 0; u < 16; ++u) sc[u] = scs[t*16 + u];
    sc[tt] = -3.0e38f;
    for (int kk = 0; kk < 4; ++kk){
      float best = -3.4e38f; int bi = 0;
#pragma unroll
      for (int u = 0; u < 16; ++u) if (sc[u] > best){ best = sc[u]; bi = u; }
      routes[t*4 + kk] = bi;
      sc[bi] = -3.4e38f;
    }
  }
}

// ---------------- K3: fused LN + wormhole-MLP + residual (v13, PROVEN BEST 94.7us) ------
// 512 blocks x 8 quads, LDS 40960, bounds (256,2). Envelope locked (r4-r16 ledger):
// bounds>2 / LDS>40KB launch-dead; barrier elision races; volatile-diet & reg-hoist regress.
#define MFMA16(accv, av, bbv) accv = __builtin_amdgcn_mfma_f32_16x16x32_bf16(av, bbv, accv, 0, 0, 0)

__global__ __launch_bounds__(256, 2) void wk_main(const float* __restrict__ x,
    const float* __restrict__ gm, const float* __restrict__ bt,
    const float* __restrict__ b1, const float* __restrict__ b2p,
    const unsigned short* __restrict__ W1bf, const unsigned short* __restrict__ W2bf,
    const int* __restrict__ routes, float* __restrict__ out){
  __shared__ char sm[40960];
  const int tid = threadIdx.x, w = tid >> 6, lane = tid & 63;
  const int c = lane & 15, g = lane >> 4;
  char* xnb = sm;            // [row r][2048B], XOR-swizzled by tile
  char* Hb  = sm + 8192;     // [row r][4096B]: [tile c][dim*2], XOR (c&7)<<4
  char* W2s = sm + 24576;    // [64 rows][256B], XOR (row&7)<<4
#pragma unroll
  for (int q = 0; q < 4; ++q){
    const int cid = tid*4 + q, row = cid >> 4, k16 = cid & 15;
    *(int4*)(W2s + row*256 + ((k16*16) ^ ((row & 7) << 4))) = *(const int4*)(W2bf + row*128 + k16*8);
  }
  // W1 m-slice -> registers: lane (c,g) holds W1[(2w+mi)*16+c][kk*32+g*8+e]
  bf16x8 w1f[2][10];
#pragma unroll
  for (int mi = 0; mi < 2; ++mi)
#pragma unroll
    for (int kk = 0; kk < 10; ++kk)
      w1f[mi][kk] = *(const bf16x8*)(W1bf + ((2*w + mi)*16 + c)*320 + kk*32 + g*8);
  floatx4 gvv[4], bvv[4];
#pragma unroll
  for (int j = 0; j < 4; ++j){
    gvv[j] = *(const floatx4*)(gm + j*256 + lane*4);
    bvv[j] = *(const floatx4*)(bt + j*256 + lane*4);
  }
  floatx4 b1v[2];
#pragma unroll
  for (int mi = 0; mi < 2; ++mi) b1v[mi] = *(const floatx4*)(b1 + (2*w + mi)*16 + g*4);
  float b2v[4];
#pragma unroll
  for (int nn = 0; nn < 4; ++nn) b2v[nn] = b2p[nn*16 + c];
  const int bbat = blockIdx.x >> 7;    // 128 blocks per batch
  const int4 rt4 = *(const int4*)(routes + (bbat*16 + c)*4);
  const int rts[5] = {c, rt4.x, rt4.y, rt4.z, rt4.w};
  const int swc = (c & 7) << 4;
  const int g16 = g * 16;

#pragma unroll 1
  for (int q = 0; q < 8; ++q){
    const int row = blockIdx.x*32 + q*4 + w;
    // ---- LN for this wave's row (coalesced float4), keep x in regs for residual
    const float* xr = x + (size_t)row * 1024;
    floatx4 xv[4];
#pragma unroll
    for (int j = 0; j < 4; ++j) xv[j] = *(const floatx4*)(xr + j*256 + lane*4);
    float s = 0.f, s2 = 0.f;
#pragma unroll
    for (int j = 0; j < 4; ++j)
#pragma unroll
      for (int e = 0; e < 4; ++e){ float v = xv[j][e]; s += v; s2 += v*v; }
    s = wred64(s); s2 = wred64(s2);
    const float mu = s * (1.0f/1024.0f);
    const float rs = rsqrtf(s2 * (1.0f/1024.0f) - mu*mu + 1e-5f);
#pragma unroll
    for (int j = 0; j < 4; ++j){
      floatx4 xn = (xv[j] - mu) * rs * gvv[j] + bvv[j];
      uint2 pv; pv.x = pk2(xn[0], xn[1]); pv.y = pk2(xn[2], xn[3]);
      const int o = j*512 + lane*8;
      *(uint2*)(xnb + w*2048 + (o ^ (((o >> 7) & 7) << 4))) = pv;
    }
    __syncthreads();   // bar A: xn visible
    // ---- GEMM1: H[m-slice][tile c] for 4 quad-rows, W1 from regs, xn from LDS
    floatx4 acc[4][2];
#pragma unroll
    for (int r = 0; r < 4; ++r)
#pragma unroll
      for (int mi = 0; mi < 2; ++mi){ acc[r][mi][0]=0.f; acc[r][mi][1]=0.f; acc[r][mi][2]=0.f; acc[r][mi][3]=0.f; }
#pragma unroll
    for (int kk = 0; kk < 10; ++kk){
      const int s_ = rts[kk >> 1];
      const int baddr = (s_*128 + (kk & 1)*64 + g16) ^ ((s_ & 7) << 4);
      bf16x8 bfr[4];
#pragma unroll
      for (int r = 0; r < 4; ++r) bfr[r] = *(const bf16x8*)(xnb + r*2048 + baddr);
#pragma unroll
      for (int r = 0; r < 4; ++r)
#pragma unroll
        for (int mi = 0; mi < 2; ++mi)
          MFMA16(acc[r][mi], w1f[mi][kk], bfr[r]);
    }
    // ---- bias + GELU -> Hb (bf16)
#pragma unroll
    for (int r = 0; r < 4; ++r)
#pragma unroll
      for (int mi = 0; mi < 2; ++mi){
        floatx4 z = acc[r][mi] + b1v[mi];
        uint2 pv; pv.x = pk2(gelu_f(z[0]), gelu_f(z[1])); pv.y = pk2(gelu_f(z[2]), gelu_f(z[3]));
        *(uint2*)(Hb + r*4096 + c*256 + ((((2*w + mi)*32) + g*8) ^ swc)) = pv;
      }
    __syncthreads();   // bar B: H visible
    // ---- GEMM2 for this wave's row (Hb[w] + W2s)
    floatx4 a2c[4];
#pragma unroll
    for (int n = 0; n < 4; ++n){ a2c[n][0]=0.f; a2c[n][1]=0.f; a2c[n][2]=0.f; a2c[n][3]=0.f; }
#pragma unroll
    for (int k2 = 0; k2 < 4; ++k2){
      const bf16x8 a2 = *(const bf16x8*)(Hb + w*4096 + c*256 + (((k2*64) + g16) ^ swc));
#pragma unroll
      for (int n = 0; n < 4; ++n){
        const bf16x8 b2f = *(const bf16x8*)(W2s + (n*16 + c)*256 + (((k2*64) + g16) ^ swc));
        MFMA16(a2c[n], a2, b2f);
      }
    }
    // ---- O -> LDS (overlay Hb[w], wave-private, XOR word idx by (orow&7)<<2) -> float4 store
    float* Ob = (float*)(Hb + w*4096);
#pragma unroll
    for (int n = 0; n < 4; ++n)
#pragma unroll
      for (int reg = 0; reg < 4; ++reg){
        const int orow = g*4 + reg;
        Ob[orow*64 + ((n*16 + c) ^ ((orow & 7) << 2))] = a2c[n][reg] + b2v[n];
      }
    float* op = out + (size_t)row * 1024;
#pragma unroll
    for (int j = 0; j < 4; ++j){
      const int orow = j*4 + g;
      const floatx4 ov = *(const floatx4*)(Ob + orow*64 + ((c*4) ^ ((orow & 7) << 2)));
      *(floatx4*)(op + j*256 + lane*4) = ov + xv[j];
    }
    __syncthreads();   // bar C
  }
}

extern "C" void kernel_launch(void* const* d_in, const int* in_sizes, int n_in,
                              void* d_out, int out_size, void* d_ws, size_t ws_size,
                              hipStream_t stream){
  const float* x  = (const float*)d_in[0];
  const float* gm = (const float*)d_in[1];
  const float* bt = (const float*)d_in[2];
  const float* Wq = (const float*)d_in[3];
  const float* bq = (const float*)d_in[4];
  const float* Wk = (const float*)d_in[5];
  const float* bk = (const float*)d_in[6];
  const float* W1 = (const float*)d_in[7];
  const float* b1 = (const float*)d_in[8];
  const float* W2 = (const float*)d_in[9];
  const float* b2 = (const float*)d_in[10];
  float* out = (float*)d_out;
  char* ws = (char*)d_ws;
  float* part = (float*)ws;                         // 512*1024 f32 = 2MB
  float* trep = part + 512*1024;                    // 4096 f32
  int*   routes = (int*)(trep + 4096);              // 256 i32
  unsigned short* W1bf = (unsigned short*)(ws + 2114560);  // 40960 bf16 (linear)
  unsigned short* W2bf = (unsigned short*)(ws + 2196480);  // 8192 bf16 (linear)

  wk_ln_part<<<512, 256, 0, stream>>>(x, gm, bt, part);
  wk_reduce<<<64, 256, 0, stream>>>(part, trep, W1, W2, W1bf, W2bf);
  wk_route<<<1, 256, 0, stream>>>(trep, Wq, bq, Wk, bk, routes);
  wk_main<<<512, 256, 0, stream>>>(x, gm, bt, b1, b2, W1bf, W2bf, routes, out);
}